// Round 17
// baseline (776.359 us; speedup 1.0000x reference)
//
#include <hip/hip_runtime.h>
#include <stdint.h>

#define LOG2E_F 1.4426950408889634f
#define LN2_D   0.6931471805599453
#define SEQLEN  16384
#define NTAGS   1024
#define TPB     512
#define NGROUP  32        // 16 fwd + 16 bwd groups
#define GPB     4         // blocks per group (256 rows each)
#define ROWS    256
#define CPG     32        // chunk-columns per group (2 MFMA B-tiles)
#define LSEG    32        // steps per chunk
#define KCH     512       // chunks per direction
#define COFF    13.0f
#define GUARD_MAX 100000
#define PARW    (CPG * 256)   // tagless wire: 256 u32 (1024 fp8 rows) per col
#define KSTRIDE 129           // uint2 stride per kk: 516 dwords = 4 mod 32 -> 2-way free
#define NAUX    17            // 16 emit blocks + 1 trans block (co-resident: 145 <= 256)

typedef float f32x2 __attribute__((ext_vector_type(2)));
typedef float f32x4 __attribute__((ext_vector_type(4)));
typedef uint32_t u32;
typedef uint64_t u64;

#define REP4(M, B)   M(B) M((B)+1) M((B)+2) M((B)+3)
#define REP16(M, B)  REP4(M, B) REP4(M, (B)+4) REP4(M, (B)+8) REP4(M, (B)+12)
#define REP32(M, B)  REP16(M, B) REP16(M, (B)+16)

#if __has_builtin(__builtin_amdgcn_cvt_pk_fp8_f32) && __has_builtin(__builtin_amdgcn_cvt_pk_f32_fp8)
__device__ __forceinline__ u32 pack4_fp8(float x0, float x1, float x2, float x3) {
    int v = __builtin_amdgcn_cvt_pk_fp8_f32(x0, x1, 0, false);
    v = __builtin_amdgcn_cvt_pk_fp8_f32(x2, x3, v, true);
    return (u32)v;
}
__device__ __forceinline__ float dec8(u32 b) {
    f32x2 r = (f32x2)__builtin_amdgcn_cvt_pk_f32_fp8((int)(b & 0xFFu), false);
    return r.x;
}
#else
__device__ __forceinline__ u32 enc1_fp8(float x) {
    if (x >= 448.f) return 0x7Eu;
    if (x < 0.015625f) { int m = (int)(x * 512.f + 0.5f); return (u32)m; }
    u32 u = __float_as_uint(x);
    u += 0x7FFFFu + ((u >> 20) & 1u);
    int e32 = (int)(u >> 23) - 127;
    if (e32 > 8) return 0x7Eu;
    return (u32)(((e32 + 7) << 3) | ((u >> 20) & 7u));
}
__device__ __forceinline__ u32 pack4_fp8(float x0, float x1, float x2, float x3) {
    return enc1_fp8(x0) | (enc1_fp8(x1) << 8) | (enc1_fp8(x2) << 16) | (enc1_fp8(x3) << 24);
}
__device__ __forceinline__ float dec8(u32 b) {
    b &= 0xFFu;
    u32 e = (b >> 3) & 0xFu, m = b & 7u;
    if (e == 0) return (float)m * 0.001953125f;
    return __uint_as_float(((e + 120u) << 23) | (m << 20));
}
#endif

// prep: clear block-level flags (NGROUP x [parity][rank])
__global__ void crf_prep_k(u32* __restrict__ flags) {
    const int tid = threadIdx.x;   // 256
    for (int i = tid; i < NGROUP * 16; i += 256)
        __hip_atomic_store(&flags[i], 0xFFFFu, __ATOMIC_RELAXED, __HIP_MEMORY_SCOPE_AGENT);
}

__global__ __launch_bounds__(TPB, 1) void crf_scan_k(
    const float* __restrict__ feats, const float* __restrict__ trans,
    const int* __restrict__ tags, const int* __restrict__ start_p,
    u32* __restrict__ wbufs, u32* __restrict__ flags, double* __restrict__ Ssum,
    float* __restrict__ part, float* __restrict__ tsum)
{
    extern __shared__ uint2 wBf[];       // [2][32][KSTRIDE] MFMA B slots (scan role)
    __shared__ u32 cmaxb[2][CPG];
    __shared__ float fbx[8][16][17];     // fallback transpose buffer
    __shared__ int okf, deadf;

    const int tid = threadIdx.x;

    // ---- aux role: blocks 128..144 (co-resident with the 128 scan blocks) ----
    if (blockIdx.x >= NGROUP * GPB) {
        const int bb = blockIdx.x - NGROUP * GPB;
        u32* ldsraw = (u32*)wBf;
        if (bb < 16) {                   // emit: part[cch][j] = sum_k feats[tg[k]][j]
            int* tg = (int*)ldsraw;
            const int cch = bb >> 1, jb = bb & 1;
            for (int q = tid; q < 2048; q += TPB) tg[q] = tags[cch * 2048 + q];
            __syncthreads();
            const int j = jb * 512 + tid;
            float acc = 0.f;
#pragma unroll 8
            for (int k = 0; k < 2048; ++k) acc += feats[(size_t)tg[k] * NTAGS + j];
            part[cch * NTAGS + j] = acc;
        } else {                         // trans-sum (gold transition score)
            float* red = (float*)ldsraw;
            const int start = *start_p;
            float acc = 0.f;
            for (int k = 0; k < 32; ++k) {
                const int t = tid * 32 + k;
                const int prev = (t == 0) ? start : tags[t - 1];
                acc += trans[(size_t)tags[t] * NTAGS + prev];
            }
            red[tid] = acc;
            __syncthreads();
            for (int s = 256; s > 0; s >>= 1) {
                if (tid < s) red[tid] += red[tid + s];
                __syncthreads();
            }
            if (tid == 0) *tsum = red[0];
        }
        return;
    }

    const int l = tid & 63, wv = tid >> 6;
    const int g = blockIdx.x & 31, rank = blockIdx.x >> 5;   // rank 0..3, 32 apart
    const int bwd = g >> 4, gl = g & 15;
    const int row0 = rank * ROWS;
    const int pc = tid >> 4, pq = tid & 15;    // reader: col 0..31, word-slice 0..15
    const int myc = l & 15, h = l >> 4;
    const int growA0 = row0 + wv * 32 + myc;   // row tile 0 A row
    const int growA1 = growA0 + 16;            // row tile 1 A row
    const int growD0 = row0 + wv * 32 + h * 4; // row tile 0 D rows (4 consecutive)
    const int growD1 = growD0 + 16;
    const int sb = (pc >> 4) * 64 + (pc & 15);
    u32* wgrp = wbufs + (size_t)g * (2 * PARW);
    u32* fgrp = flags + g * 16;                // [parity][rank]

    if (tid == 0) { okf = 1; deadf = 0; }
    double Sacc = bwd ? 3.0 : 0.0;             // meaningful for tid < CPG

    // ---- init publish (parity 0), tagless: block's 256 rows x 32 cols ----
    for (int f = tid; f < CPG * 64; f += TPB) {
        const int c = f >> 6, q = f & 63;      // col, word-in-block (4 rows/word)
        u32 pk;
        if (!bwd) pk = 0x38383838u;            // fp8(1.0) x4
        else {
            const int t = (gl * CPG + c) * LSEG + LSEG - 1;
            const int j0 = row0 + 4 * q;
            const float4 fv = *(const float4*)&feats[(size_t)t * NTAGS + j0];
            pk = pack4_fp8(exp2f(fv.x * LOG2E_F - 3.0f), exp2f(fv.y * LOG2E_F - 3.0f),
                           exp2f(fv.z * LOG2E_F - 3.0f), exp2f(fv.w * LOG2E_F - 3.0f));
        }
        __hip_atomic_store(&wgrp[c * 256 + (row0 >> 2) + q], pk,
                           __ATOMIC_RELAXED, __HIP_MEMORY_SCOPE_AGENT);
    }
    asm volatile("s_waitcnt vmcnt(0)" ::: "memory");
    __syncthreads();
    if (tid == 0)
        __hip_atomic_store(&fgrp[0 * 8 + rank], 0u, __ATOMIC_RELAXED, __HIP_MEMORY_SCOPE_AGENT);

    // ---- stage E as persistent A-fragments (fp8): 2 row tiles, 128 VGPR ----
    u64 afr0[32], afr1[32];
#define STG(KK, AFR, GROW) { \
        const int kb = (KK) * 32 + h * 8; \
        float x0,x1,x2,x3,x4,x5,x6,x7; \
        if (!bwd) { \
            const float4 t0 = *(const float4*)&trans[(size_t)(GROW) * NTAGS + kb]; \
            const float4 t1 = *(const float4*)&trans[(size_t)(GROW) * NTAGS + kb + 4]; \
            x0=t0.x; x1=t0.y; x2=t0.z; x3=t0.w; x4=t1.x; x5=t1.y; x6=t1.z; x7=t1.w; \
        } else { \
            x0 = trans[(size_t)(kb+0)*NTAGS + (GROW)]; x1 = trans[(size_t)(kb+1)*NTAGS + (GROW)]; \
            x2 = trans[(size_t)(kb+2)*NTAGS + (GROW)]; x3 = trans[(size_t)(kb+3)*NTAGS + (GROW)]; \
            x4 = trans[(size_t)(kb+4)*NTAGS + (GROW)]; x5 = trans[(size_t)(kb+5)*NTAGS + (GROW)]; \
            x6 = trans[(size_t)(kb+6)*NTAGS + (GROW)]; x7 = trans[(size_t)(kb+7)*NTAGS + (GROW)]; \
        } \
        const u32 lo = pack4_fp8(exp2f(x0*LOG2E_F), exp2f(x1*LOG2E_F), exp2f(x2*LOG2E_F), exp2f(x3*LOG2E_F)); \
        const u32 hi = pack4_fp8(exp2f(x4*LOG2E_F), exp2f(x5*LOG2E_F), exp2f(x6*LOG2E_F), exp2f(x7*LOG2E_F)); \
        AFR[KK] = (u64)lo | ((u64)hi << 32); }
#define STG0(KK) STG(KK, afr0, growA0)
#define STG1(KK) STG(KK, afr1, growA1)
    REP32(STG0, 0)
    REP32(STG1, 0)
#undef STG0
#undef STG1
#undef STG

    // ---- MFMA layout self-check (exact small-int, asymmetric) — R10-proven ----
    {
        float av0,av1,av2,av3,av4,av5,av6,av7, bv0,bv1,bv2,bv3,bv4,bv5,bv6,bv7;
#define TV(I) { const int k = h*8 + (I); \
        const float a_ = (float)((myc + k) & 3); \
        const float b_ = (float)(((k ^ myc) & 3) + 1); \
        if ((I)==0){av0=a_;bv0=b_;} if ((I)==1){av1=a_;bv1=b_;} \
        if ((I)==2){av2=a_;bv2=b_;} if ((I)==3){av3=a_;bv3=b_;} \
        if ((I)==4){av4=a_;bv4=b_;} if ((I)==5){av5=a_;bv5=b_;} \
        if ((I)==6){av6=a_;bv6=b_;} if ((I)==7){av7=a_;bv7=b_;} }
        TV(0) TV(1) TV(2) TV(3) TV(4) TV(5) TV(6) TV(7)
#undef TV
        const u64 at = (u64)pack4_fp8(av0,av1,av2,av3) | ((u64)pack4_fp8(av4,av5,av6,av7) << 32);
        const u64 bt = (u64)pack4_fp8(bv0,bv1,bv2,bv3) | ((u64)pack4_fp8(bv4,bv5,bv6,bv7) << 32);
        f32x4 dz = {0.f, 0.f, 0.f, 0.f};
        dz = __builtin_amdgcn_mfma_f32_16x16x32_fp8_fp8((long)at, (long)bt, dz, 0, 0, 0);
        bool good = true;
#pragma unroll
        for (int v = 0; v < 4; ++v) {
            const int row = h * 4 + v;
            float e = 0.f;
            for (int k = 0; k < 32; ++k)
                e += (float)(((row + k) & 3) * (((k ^ myc) & 3) + 1));
            good = good && (dz[v] == e);
        }
        if (!good) okf = 0;
    }
    __syncthreads();
    const bool fb = (okf == 0);

    for (int tau = 0; tau < LSEG; ++tau) {
        const int p = tau & 1;
        const u32 tag = (u32)tau;

        // feat prefetch (2 row tiles x 2 col tiles), issued before discovery
        float4 ffa0 = make_float4(0,0,0,0), ffb0 = make_float4(0,0,0,0);
        float4 ffa1 = make_float4(0,0,0,0), ffb1 = make_float4(0,0,0,0);
        {
            int t = -1;
            if (!bwd) t = tau; else if (tau <= LSEG - 2) t = LSEG - 2 - tau;
            if (t >= 0) {
                const int ca = gl * CPG + myc;
                const size_t ba = (size_t)(ca * LSEG + t) * NTAGS;
                const size_t bb2 = (size_t)((ca + 16) * LSEG + t) * NTAGS;
                ffa0 = *(const float4*)&feats[ba + growD0];
                ffb0 = *(const float4*)&feats[bb2 + growD0];
                ffa1 = *(const float4*)&feats[ba + growD1];
                ffb1 = *(const float4*)&feats[bb2 + growD1];
            }
        }

        // ---- 1. flag discovery: wave 0 only (4 words) ----
        if (wv == 0) {
            int guard = 0;
            u32 fv = tag;
            for (;;) {
                if (l < GPB)
                    fv = __hip_atomic_load(&fgrp[p * 8 + l],
                                           __ATOMIC_RELAXED, __HIP_MEMORY_SCOPE_AGENT);
                if (__all(fv == tag)) break;
                if (++guard > GUARD_MAX) { deadf = 1; break; }
            }
        }
        __syncthreads();               // flags seen; deadf visible
        if (deadf) break;

        // ---- 2. tagless bulk read: 16 words = 64 rows of col pc ----
        u32 w[16];
        {
            const u32* pp = wgrp + p * PARW + pc * 256 + pq * 16;
#pragma unroll
            for (int q = 0; q < 8; ++q) {
                const u64 v = __hip_atomic_load((const u64*)(pp + 2 * q),
                                                __ATOMIC_RELAXED, __HIP_MEMORY_SCOPE_AGENT);
                w[2 * q] = (u32)v; w[2 * q + 1] = (u32)(v >> 32);
            }
        }
        // B-slot writes (stride KSTRIDE: 2-way bank aliasing only)
        {
#pragma unroll
            for (int h2 = 0; h2 < 4; ++h2) {
                wBf[((size_t)p * 32 + 2 * pq)     * KSTRIDE + sb + h2 * 16] = make_uint2(w[2*h2],   w[2*h2+1]);
                wBf[((size_t)p * 32 + 2 * pq + 1) * KSTRIDE + sb + h2 * 16] = make_uint2(w[8+2*h2], w[9+2*h2]);
            }
        }
        // col byte-max (fp8 e4m3 positive: integer order = value order)
        {
            u32 bm = 0;
#pragma unroll
            for (int q = 0; q < 16; ++q) {
                bm = max(bm, w[q] & 0xFFu); bm = max(bm, (w[q] >> 8) & 0xFFu);
                bm = max(bm, (w[q] >> 16) & 0xFFu); bm = max(bm, w[q] >> 24);
            }
#pragma unroll
            for (int o = 8; o > 0; o >>= 1) bm = max(bm, (u32)__shfl_xor((int)bm, o));
            if (pq == 0) cmaxb[p][pc] = bm;
        }
        __syncthreads();                 // B1: slots + cmax ready

        const float Cme0 = __log2f(dec8(cmaxb[p][myc])) + COFF;
        const float Cme1 = __log2f(dec8(cmaxb[p][16 + myc])) + COFF;
        if (tid < CPG) Sacc += (double)(__log2f(dec8(cmaxb[p][tid])) + COFF);

        // ---- 3. D = E(256x1024) x w(1024x32): 2 row tiles x 2 col tiles ----
        f32x4 accA0, accB0, accA1, accB1;
        const uint2* wb = &wBf[(size_t)p * 32 * KSTRIDE];
        if (!fb) {
            f32x4 q0 = {0,0,0,0}, q1 = {0,0,0,0}, r0 = {0,0,0,0}, r1 = {0,0,0,0};
            f32x4 s0 = {0,0,0,0}, s1 = {0,0,0,0}, t0 = {0,0,0,0}, t1 = {0,0,0,0};
#define MF(KK) { const uint2 f0 = wb[(KK)*KSTRIDE + l]; \
                 const u64 b0 = (u64)f0.x | ((u64)f0.y << 32); \
                 const uint2 f1 = wb[(KK)*KSTRIDE + 64 + l]; \
                 const u64 b1v = (u64)f1.x | ((u64)f1.y << 32); \
                 if ((KK) & 1) { \
                     q1 = __builtin_amdgcn_mfma_f32_16x16x32_fp8_fp8((long)afr0[KK], (long)b0, q1, 0,0,0); \
                     r1 = __builtin_amdgcn_mfma_f32_16x16x32_fp8_fp8((long)afr0[KK], (long)b1v, r1, 0,0,0); \
                     s1 = __builtin_amdgcn_mfma_f32_16x16x32_fp8_fp8((long)afr1[KK], (long)b0, s1, 0,0,0); \
                     t1 = __builtin_amdgcn_mfma_f32_16x16x32_fp8_fp8((long)afr1[KK], (long)b1v, t1, 0,0,0); \
                 } else { \
                     q0 = __builtin_amdgcn_mfma_f32_16x16x32_fp8_fp8((long)afr0[KK], (long)b0, q0, 0,0,0); \
                     r0 = __builtin_amdgcn_mfma_f32_16x16x32_fp8_fp8((long)afr0[KK], (long)b1v, r0, 0,0,0); \
                     s0 = __builtin_amdgcn_mfma_f32_16x16x32_fp8_fp8((long)afr1[KK], (long)b0, s0, 0,0,0); \
                     t0 = __builtin_amdgcn_mfma_f32_16x16x32_fp8_fp8((long)afr1[KK], (long)b1v, t0, 0,0,0); \
                 } }
            REP32(MF, 0)
#undef MF
            accA0 = q0 + q1; accB0 = r0 + r1; accA1 = s0 + s1; accB1 = t0 + t1;
        } else {
            // layout-assumption-free VALU fallback (slow, correct)
#define FBT(AFR, OUTA, OUTB) { \
            for (int bt = 0; bt < 2; ++bt) { \
                float a16[16]; \
                for (int c = 0; c < 16; ++c) a16[c] = 0.f; \
                for (int kk = 0; kk < 32; ++kk) { \
                    const u64 av = AFR[kk]; \
                    float ea0 = dec8((u32)av), ea1 = dec8((u32)(av>>8)), ea2 = dec8((u32)(av>>16)), ea3 = dec8((u32)(av>>24)); \
                    float ea4 = dec8((u32)(av>>32)), ea5 = dec8((u32)(av>>40)), ea6 = dec8((u32)(av>>48)), ea7 = dec8((u32)(av>>56)); \
                    for (int c = 0; c < 16; ++c) { \
                        const uint2 bfr = wb[kk * KSTRIDE + bt * 64 + h * 16 + c]; \
                        const u64 bv = (u64)bfr.x | ((u64)bfr.y << 32); \
                        float s = fmaf(ea0, dec8((u32)bv), 0.f); \
                        s = fmaf(ea1, dec8((u32)(bv>>8)), s);  s = fmaf(ea2, dec8((u32)(bv>>16)), s); \
                        s = fmaf(ea3, dec8((u32)(bv>>24)), s); s = fmaf(ea4, dec8((u32)(bv>>32)), s); \
                        s = fmaf(ea5, dec8((u32)(bv>>40)), s); s = fmaf(ea6, dec8((u32)(bv>>48)), s); \
                        s = fmaf(ea7, dec8((u32)(bv>>56)), s); \
                        a16[c] += s; \
                    } \
                } \
                for (int c = 0; c < 16; ++c) { \
                    float v2 = a16[c]; \
                    v2 += __shfl_xor(v2, 16); v2 += __shfl_xor(v2, 32); \
                    a16[c] = v2; \
                } \
                if (h == 0) { for (int c = 0; c < 16; ++c) fbx[wv][myc][c] = a16[c]; } \
                __syncthreads(); \
                f32x4 r; \
                r.x = fbx[wv][h*4+0][myc]; r.y = fbx[wv][h*4+1][myc]; \
                r.z = fbx[wv][h*4+2][myc]; r.w = fbx[wv][h*4+3][myc]; \
                if (bt == 0) OUTA = r; else OUTB = r; \
                __syncthreads(); \
            } }
            FBT(afr0, accA0, accB0)
            FBT(afr1, accA1, accB1)
#undef FBT
        }

        // ---- 4. publish -> parity p^1 (4 words); drain; barrier; block flag ----
        {
            u32* pb = wgrp + (p ^ 1) * PARW;
            const u32 pkA0 = pack4_fp8(accA0.x * exp2f(fmaf(ffa0.x, LOG2E_F, -Cme0)),
                                       accA0.y * exp2f(fmaf(ffa0.y, LOG2E_F, -Cme0)),
                                       accA0.z * exp2f(fmaf(ffa0.z, LOG2E_F, -Cme0)),
                                       accA0.w * exp2f(fmaf(ffa0.w, LOG2E_F, -Cme0)));
            const u32 pkB0 = pack4_fp8(accB0.x * exp2f(fmaf(ffb0.x, LOG2E_F, -Cme1)),
                                       accB0.y * exp2f(fmaf(ffb0.y, LOG2E_F, -Cme1)),
                                       accB0.z * exp2f(fmaf(ffb0.z, LOG2E_F, -Cme1)),
                                       accB0.w * exp2f(fmaf(ffb0.w, LOG2E_F, -Cme1)));
            const u32 pkA1 = pack4_fp8(accA1.x * exp2f(fmaf(ffa1.x, LOG2E_F, -Cme0)),
                                       accA1.y * exp2f(fmaf(ffa1.y, LOG2E_F, -Cme0)),
                                       accA1.z * exp2f(fmaf(ffa1.z, LOG2E_F, -Cme0)),
                                       accA1.w * exp2f(fmaf(ffa1.w, LOG2E_F, -Cme0)));
            const u32 pkB1 = pack4_fp8(accB1.x * exp2f(fmaf(ffb1.x, LOG2E_F, -Cme1)),
                                       accB1.y * exp2f(fmaf(ffb1.y, LOG2E_F, -Cme1)),
                                       accB1.z * exp2f(fmaf(ffb1.z, LOG2E_F, -Cme1)),
                                       accB1.w * exp2f(fmaf(ffb1.w, LOG2E_F, -Cme1)));
            __hip_atomic_store(&pb[myc * 256 + (growD0 >> 2)], pkA0,
                               __ATOMIC_RELAXED, __HIP_MEMORY_SCOPE_AGENT);
            __hip_atomic_store(&pb[(16 + myc) * 256 + (growD0 >> 2)], pkB0,
                               __ATOMIC_RELAXED, __HIP_MEMORY_SCOPE_AGENT);
            __hip_atomic_store(&pb[myc * 256 + (growD1 >> 2)], pkA1,
                               __ATOMIC_RELAXED, __HIP_MEMORY_SCOPE_AGENT);
            __hip_atomic_store(&pb[(16 + myc) * 256 + (growD1 >> 2)], pkB1,
                               __ATOMIC_RELAXED, __HIP_MEMORY_SCOPE_AGENT);
        }
        asm volatile("s_waitcnt vmcnt(0)" ::: "memory");   // this wave's stores acked
        __syncthreads();                                    // all waves acked
        if (tid == 0)
            __hip_atomic_store(&fgrp[(p ^ 1) * 8 + rank], tag + 1u,
                               __ATOMIC_RELAXED, __HIP_MEMORY_SCOPE_AGENT);
    }

    if (rank == 0 && tid < CPG)
        Ssum[bwd * KCH + gl * CPG + tid] = Sacc;
}

// dots: sumy[c]=1'y_c ; dot[c]=z_c.y_{c-1} (c>0), dot[0]=z_0[start]; fin=y_{K-1}.exp(T[stop,:])
__global__ void crf_dots_k(const u32* __restrict__ wbufs, const float* __restrict__ trans,
                           const int* __restrict__ start_p, const int* __restrict__ stop_p,
                           double* __restrict__ dotv, double* __restrict__ sumyv,
                           double* __restrict__ finv)
{
    const int c = blockIdx.x;        // 0..511
    const int tid = threadIdx.x;     // 256 (one word each; 4 rows/word)
    __shared__ double red[256];
    const int GRPW = 2 * PARW;
    const u32* y = wbufs + (size_t)(c >> 5) * GRPW + (c & 31) * 256;
    const u32* z = wbufs + (size_t)(16 + (c >> 5)) * GRPW + (c & 31) * 256;
    const u32* ym1 = (c > 0)
        ? (wbufs + (size_t)((c - 1) >> 5) * GRPW + ((c - 1) & 31) * 256) : nullptr;
    const int stop = *stop_p;

    const u32 wy = y[tid];
    double sy = 0, dt = 0, fn = 0;
#pragma unroll
    for (int b = 0; b < 4; ++b) {
        const double yv = (double)dec8(wy >> (8 * b));
        sy += yv;
        if (c == KCH - 1)
            fn += yv * (double)__expf(trans[(size_t)stop * NTAGS + 4 * tid + b]);
    }
    if (c > 0) {
        const u32 wz = z[tid], wm = ym1[tid];
#pragma unroll
        for (int b = 0; b < 4; ++b)
            dt += (double)dec8(wz >> (8 * b)) * (double)dec8(wm >> (8 * b));
    }
    red[tid] = sy; __syncthreads();
    for (int s = 128; s > 0; s >>= 1) { if (tid < s) red[tid] += red[tid + s]; __syncthreads(); }
    if (tid == 0) sumyv[c] = red[0];
    __syncthreads();
    red[tid] = dt; __syncthreads();
    for (int s = 128; s > 0; s >>= 1) { if (tid < s) red[tid] += red[tid + s]; __syncthreads(); }
    if (tid == 0 && c > 0) dotv[c] = red[0];
    __syncthreads();
    red[tid] = fn; __syncthreads();
    for (int s = 128; s > 0; s >>= 1) { if (tid < s) red[tid] += red[tid + s]; __syncthreads(); }
    if (tid == 0 && c == KCH - 1) finv[0] = red[0];
    if (tid == 0 && c == 0) {
        const int st = *start_p;
        dotv[0] = (double)dec8(z[st >> 2] >> (8 * (st & 3)));
    }
}

// finish: parallel chunk-composition (fs) + output vector
__global__ void crf_finish_k(const double* __restrict__ Ssum, const double* __restrict__ dotv,
                             const double* __restrict__ sumyv, const double* __restrict__ finv,
                             const float* __restrict__ tsum, const float* __restrict__ part,
                             const float* __restrict__ trans, const int* __restrict__ tags,
                             const int* __restrict__ stop_p, float* __restrict__ out)
{
    __shared__ double red[1024];
    __shared__ float fsv;
    const int tid = threadIdx.x;   // 1024
    const double* Ssf = Ssum;
    const double* Ssb = Ssum + KCH;
    double t = 0.0;
    if (tid == 0)
        t = log2(dotv[0]) + Ssb[0] - log2(sumyv[0]) - Ssf[0]
          + log2(finv[0]) + Ssf[KCH - 1];
    else if (tid < KCH)
        t = log2(dotv[tid]) + Ssb[tid] + Ssf[tid - 1] - log2(sumyv[tid]) - Ssf[tid];
    red[tid] = t; __syncthreads();
    for (int s = 512; s > 0; s >>= 1) { if (tid < s) red[tid] += red[tid + s]; __syncthreads(); }
    if (tid == 0) fsv = (float)(LN2_D * red[0]);
    __syncthreads();
    float e = 0.f;
    for (int cc = 0; cc < 8; ++cc) e += part[cc * NTAGS + tid];
    const int stop = *stop_p;
    const int last = tags[SEQLEN - 1];
    out[tid] = fsv - (tsum[0] + e + trans[(size_t)stop * NTAGS + last]);
}

extern "C" void kernel_launch(void* const* d_in, const int* in_sizes, int n_in,
                              void* d_out, int out_size, void* d_ws, size_t ws_size,
                              hipStream_t stream) {
    const float* feats = (const float*)d_in[0];
    const float* trans = (const float*)d_in[1];
    const int* tags    = (const int*)d_in[2];
    const int* start_p = (const int*)d_in[3];
    const int* stop_p  = (const int*)d_in[4];
    float* out = (float*)d_out;

    // ws: wire 2MB | part 32KB | Ssum 8KB | dotv 4KB | sumyv 4KB | finv/tsum | flags
    char* ws = (char*)d_ws;
    u32* wbufs    = (u32*)(ws + 0);
    float* part   = (float*)(ws + 2097152);
    double* Ssum  = (double*)(ws + 2129920);
    double* dotv  = (double*)(ws + 2138112);
    double* sumyv = (double*)(ws + 2142208);
    double* finv  = (double*)(ws + 2146304);
    float* tsum   = (float*)(ws + 2146312);
    u32* flags    = (u32*)(ws + 2146816);

    (void)hipFuncSetAttribute((const void*)crf_scan_k,
                              hipFuncAttributeMaxDynamicSharedMemorySize,
                              2 * 32 * KSTRIDE * 8);

    crf_prep_k<<<1, 256, 0, stream>>>(flags);
    crf_scan_k<<<NGROUP * GPB + NAUX, TPB, 2 * 32 * KSTRIDE * 8, stream>>>(
        feats, trans, tags, start_p, wbufs, flags, Ssum, part, tsum);
    crf_dots_k<<<KCH, 256, 0, stream>>>(wbufs, trans, start_p, stop_p, dotv, sumyv, finv);
    crf_finish_k<<<1, 1024, 0, stream>>>(Ssum, dotv, sumyv, finv, tsum, part, trans, tags,
                                         stop_p, out);
}

// Round 18
// 325.487 us; speedup vs baseline: 2.3852x; 2.3852x over previous
//
#include <hip/hip_runtime.h>
#include <stdint.h>

#define LOG2E_F 1.4426950408889634f
#define LN2_D   0.6931471805599453
#define SEQLEN  16384
#define NTAGS   1024
#define TPB     512
#define NGROUP  32        // 16 fwd + 16 bwd groups
#define GPB     8
#define ROWS    128
#define CPG     32        // chunk-columns per group (2 MFMA B-tiles)
#define LSEG    32        // steps per chunk
#define KCH     512       // chunks per direction
#define COFF    13.0f
#define GUARD_MAX 100000
#define PARW    (CPG * 256)   // tagless wire: 256 u32 (1024 fp8 rows) per col
#define KSTRIDE 129           // uint2 stride per kk: 516 dwords = 4 mod 32 -> 2-way free

typedef float f32x2 __attribute__((ext_vector_type(2)));
typedef float f32x4 __attribute__((ext_vector_type(4)));
typedef uint32_t u32;
typedef uint64_t u64;

#define REP4(M, B)   M(B) M((B)+1) M((B)+2) M((B)+3)
#define REP16(M, B)  REP4(M, B) REP4(M, (B)+4) REP4(M, (B)+8) REP4(M, (B)+12)
#define REP32(M, B)  REP16(M, B) REP16(M, (B)+16)

#if __has_builtin(__builtin_amdgcn_cvt_pk_fp8_f32) && __has_builtin(__builtin_amdgcn_cvt_pk_f32_fp8)
__device__ __forceinline__ u32 pack4_fp8(float x0, float x1, float x2, float x3) {
    int v = __builtin_amdgcn_cvt_pk_fp8_f32(x0, x1, 0, false);
    v = __builtin_amdgcn_cvt_pk_fp8_f32(x2, x3, v, true);
    return (u32)v;
}
__device__ __forceinline__ float dec8(u32 b) {
    f32x2 r = (f32x2)__builtin_amdgcn_cvt_pk_f32_fp8((int)(b & 0xFFu), false);
    return r.x;
}
#else
__device__ __forceinline__ u32 enc1_fp8(float x) {
    if (x >= 448.f) return 0x7Eu;
    if (x < 0.015625f) { int m = (int)(x * 512.f + 0.5f); return (u32)m; }
    u32 u = __float_as_uint(x);
    u += 0x7FFFFu + ((u >> 20) & 1u);
    int e32 = (int)(u >> 23) - 127;
    if (e32 > 8) return 0x7Eu;
    return (u32)(((e32 + 7) << 3) | ((u >> 20) & 7u));
}
__device__ __forceinline__ u32 pack4_fp8(float x0, float x1, float x2, float x3) {
    return enc1_fp8(x0) | (enc1_fp8(x1) << 8) | (enc1_fp8(x2) << 16) | (enc1_fp8(x3) << 24);
}
__device__ __forceinline__ float dec8(u32 b) {
    b &= 0xFFu;
    u32 e = (b >> 3) & 0xFu, m = b & 7u;
    if (e == 0) return (float)m * 0.001953125f;
    return __uint_as_float(((e + 120u) << 23) | (m << 20));
}
#endif

// prep: clear block-level flags only (1 block, ~3 us)
__global__ void crf_prep_k(u32* __restrict__ flags) {
    const int tid = threadIdx.x;   // 256
    for (int i = tid; i < NGROUP * 16; i += 256)
        __hip_atomic_store(&flags[i], 0xFFFFu, __ATOMIC_RELAXED, __HIP_MEMORY_SCOPE_AGENT);
}

__global__ __launch_bounds__(TPB, 1) void crf_scan_k(
    const float* __restrict__ feats, const float* __restrict__ trans,
    u32* __restrict__ wbufs, u32* __restrict__ flags, double* __restrict__ Ssum)
{
    extern __shared__ uint2 wBf[];       // [2][32][KSTRIDE] MFMA B slots
    __shared__ u32 cmaxb[2][CPG];
    __shared__ float fbx[8][16][17];     // fallback transpose buffer
    __shared__ int okf, deadf;

    const int tid = threadIdx.x;
    const int l = tid & 63, wv = tid >> 6;
    const int g = blockIdx.x & 31, rank = blockIdx.x >> 5;   // ranks 32 apart -> XCD co-located
    const int bwd = g >> 4, gl = g & 15;
    const int row0 = rank * ROWS;
    const int pc = tid >> 4, pq = tid & 15;    // reader: col 0..31, word-slice 0..15
    const int myc = l & 15, h = l >> 4;
    const int growA = row0 + wv * 16 + myc;
    const int growD = row0 + wv * 16 + h * 4;
    const int sb = (pc >> 4) * 64 + (pc & 15);
    u32* wgrp = wbufs + (size_t)g * (2 * PARW);
    u32* fgrp = flags + g * 16;                // [parity][rank]

    if (tid == 0) { okf = 1; deadf = 0; }
    double Sacc = bwd ? 3.0 : 0.0;             // meaningful for tid < CPG

    // ---- init publish (parity 0), tagless — R13-proven ----
    for (int f = tid; f < CPG * 32; f += TPB) {
        const int c = f >> 5, q = f & 31;      // col, word-in-block (4 rows/word)
        u32 pk;
        if (!bwd) pk = 0x38383838u;            // fp8(1.0) x4
        else {
            const int t = (gl * CPG + c) * LSEG + LSEG - 1;
            const int j0 = row0 + 4 * q;
            const float4 fv = *(const float4*)&feats[(size_t)t * NTAGS + j0];
            pk = pack4_fp8(exp2f(fv.x * LOG2E_F - 3.0f), exp2f(fv.y * LOG2E_F - 3.0f),
                           exp2f(fv.z * LOG2E_F - 3.0f), exp2f(fv.w * LOG2E_F - 3.0f));
        }
        __hip_atomic_store(&wgrp[c * 256 + (row0 >> 2) + q], pk,
                           __ATOMIC_RELAXED, __HIP_MEMORY_SCOPE_AGENT);
    }
    asm volatile("s_waitcnt vmcnt(0)" ::: "memory");   // init data acked (per wave)
    __syncthreads();                                    // all waves acked
    if (tid == 0)
        __hip_atomic_store(&fgrp[0 * 8 + rank], 0u, __ATOMIC_RELAXED, __HIP_MEMORY_SCOPE_AGENT);

    // ---- stage E as persistent A-fragments (fp8, 64 VGPR) — R10-proven ----
    u64 afr[32];
#define STG(KK) { \
        const int kb = (KK) * 32 + h * 8; \
        float x0,x1,x2,x3,x4,x5,x6,x7; \
        if (!bwd) { \
            const float4 t0 = *(const float4*)&trans[(size_t)growA * NTAGS + kb]; \
            const float4 t1 = *(const float4*)&trans[(size_t)growA * NTAGS + kb + 4]; \
            x0=t0.x; x1=t0.y; x2=t0.z; x3=t0.w; x4=t1.x; x5=t1.y; x6=t1.z; x7=t1.w; \
        } else { \
            x0 = trans[(size_t)(kb+0)*NTAGS + growA]; x1 = trans[(size_t)(kb+1)*NTAGS + growA]; \
            x2 = trans[(size_t)(kb+2)*NTAGS + growA]; x3 = trans[(size_t)(kb+3)*NTAGS + growA]; \
            x4 = trans[(size_t)(kb+4)*NTAGS + growA]; x5 = trans[(size_t)(kb+5)*NTAGS + growA]; \
            x6 = trans[(size_t)(kb+6)*NTAGS + growA]; x7 = trans[(size_t)(kb+7)*NTAGS + growA]; \
        } \
        const u32 lo = pack4_fp8(exp2f(x0*LOG2E_F), exp2f(x1*LOG2E_F), exp2f(x2*LOG2E_F), exp2f(x3*LOG2E_F)); \
        const u32 hi = pack4_fp8(exp2f(x4*LOG2E_F), exp2f(x5*LOG2E_F), exp2f(x6*LOG2E_F), exp2f(x7*LOG2E_F)); \
        afr[KK] = (u64)lo | ((u64)hi << 32); }
    REP32(STG, 0)
#undef STG

    // ---- MFMA layout self-check (exact small-int, asymmetric) — R10-proven ----
    {
        float av0,av1,av2,av3,av4,av5,av6,av7, bv0,bv1,bv2,bv3,bv4,bv5,bv6,bv7;
#define TV(I) { const int k = h*8 + (I); \
        const float a_ = (float)((myc + k) & 3); \
        const float b_ = (float)(((k ^ myc) & 3) + 1); \
        if ((I)==0){av0=a_;bv0=b_;} if ((I)==1){av1=a_;bv1=b_;} \
        if ((I)==2){av2=a_;bv2=b_;} if ((I)==3){av3=a_;bv3=b_;} \
        if ((I)==4){av4=a_;bv4=b_;} if ((I)==5){av5=a_;bv5=b_;} \
        if ((I)==6){av6=a_;bv6=b_;} if ((I)==7){av7=a_;bv7=b_;} }
        TV(0) TV(1) TV(2) TV(3) TV(4) TV(5) TV(6) TV(7)
#undef TV
        const u64 at = (u64)pack4_fp8(av0,av1,av2,av3) | ((u64)pack4_fp8(av4,av5,av6,av7) << 32);
        const u64 bt = (u64)pack4_fp8(bv0,bv1,bv2,bv3) | ((u64)pack4_fp8(bv4,bv5,bv6,bv7) << 32);
        f32x4 dz = {0.f, 0.f, 0.f, 0.f};
        dz = __builtin_amdgcn_mfma_f32_16x16x32_fp8_fp8((long)at, (long)bt, dz, 0, 0, 0);
        bool good = true;
#pragma unroll
        for (int v = 0; v < 4; ++v) {
            const int row = h * 4 + v;
            float e = 0.f;
            for (int k = 0; k < 32; ++k)
                e += (float)(((row + k) & 3) * (((k ^ myc) & 3) + 1));
            good = good && (dz[v] == e);
        }
        if (!good) okf = 0;
    }
    __syncthreads();
    const bool fb = (okf == 0);

    for (int tau = 0; tau < LSEG; ++tau) {
        const int p = tau & 1;
        const u32 tag = (u32)tau;

        // feat prefetch (both col-tiles), issued before discovery
        float4 ffa = make_float4(0.f,0.f,0.f,0.f), ffb = make_float4(0.f,0.f,0.f,0.f);
        {
            int t = -1;
            if (!bwd) t = tau; else if (tau <= LSEG - 2) t = LSEG - 2 - tau;
            if (t >= 0) {
                const int ca = gl * CPG + myc;
                ffa = *(const float4*)&feats[(size_t)(ca * LSEG + t) * NTAGS + growD];
                ffb = *(const float4*)&feats[(size_t)((ca + 16) * LSEG + t) * NTAGS + growD];
            }
        }

        // ---- 1. flag discovery: wave 0 only ----
        if (wv == 0) {
            int guard = 0;
            u32 fv = tag;
            for (;;) {
                if (l < GPB)
                    fv = __hip_atomic_load(&fgrp[p * 8 + l],
                                           __ATOMIC_RELAXED, __HIP_MEMORY_SCOPE_AGENT);
                if (__all(fv == tag)) break;
                if (++guard > GUARD_MAX) { deadf = 1; break; }
            }
        }
        __syncthreads();               // flags seen; deadf visible
        if (deadf) break;

        // ---- 2. tagless bulk read: 16 words = 64 rows of col pc ----
        u32 w[16];
        {
            const u32* pp = wgrp + p * PARW + pc * 256 + pq * 16;
#pragma unroll
            for (int q = 0; q < 8; ++q) {
                const u64 v = __hip_atomic_load((const u64*)(pp + 2 * q),
                                                __ATOMIC_RELAXED, __HIP_MEMORY_SCOPE_AGENT);
                w[2 * q] = (u32)v; w[2 * q + 1] = (u32)(v >> 32);
            }
        }
        // B-slot writes (stride KSTRIDE: 2-way bank aliasing only)
        {
#pragma unroll
            for (int h2 = 0; h2 < 4; ++h2) {
                wBf[((size_t)p * 32 + 2 * pq)     * KSTRIDE + sb + h2 * 16] = make_uint2(w[2*h2],   w[2*h2+1]);
                wBf[((size_t)p * 32 + 2 * pq + 1) * KSTRIDE + sb + h2 * 16] = make_uint2(w[8+2*h2], w[9+2*h2]);
            }
        }
        // col byte-max (fp8 e4m3 positive: integer order = value order)
        {
            u32 bm = 0;
#pragma unroll
            for (int q = 0; q < 16; ++q) {
                bm = max(bm, w[q] & 0xFFu); bm = max(bm, (w[q] >> 8) & 0xFFu);
                bm = max(bm, (w[q] >> 16) & 0xFFu); bm = max(bm, w[q] >> 24);
            }
#pragma unroll
            for (int o = 8; o > 0; o >>= 1) bm = max(bm, (u32)__shfl_xor((int)bm, o));
            if (pq == 0) cmaxb[p][pc] = bm;
        }
        __syncthreads();                 // B1: slots + cmax ready

        const float Cme0 = __log2f(dec8(cmaxb[p][myc])) + COFF;
        const float Cme1 = __log2f(dec8(cmaxb[p][16 + myc])) + COFF;
        if (tid < CPG) Sacc += (double)(__log2f(dec8(cmaxb[p][tid])) + COFF);

        // ---- 3. D = E(128x1024) x w(1024x32): 2 B-tiles, 64 MFMA ----
        f32x4 accA, accB;
        const uint2* wb = &wBf[(size_t)p * 32 * KSTRIDE];
        if (!fb) {
            f32x4 a0 = {0.f,0.f,0.f,0.f}, a1 = {0.f,0.f,0.f,0.f};
            f32x4 a2 = {0.f,0.f,0.f,0.f}, a3 = {0.f,0.f,0.f,0.f};
#define MF(KK) { const uint2 f0 = wb[(KK)*KSTRIDE + l]; \
                 const u64 b0 = (u64)f0.x | ((u64)f0.y << 32); \
                 const uint2 f1 = wb[(KK)*KSTRIDE + 64 + l]; \
                 const u64 b1v = (u64)f1.x | ((u64)f1.y << 32); \
                 if ((KK) & 1) { \
                     a1 = __builtin_amdgcn_mfma_f32_16x16x32_fp8_fp8((long)afr[KK], (long)b0, a1, 0,0,0); \
                     a3 = __builtin_amdgcn_mfma_f32_16x16x32_fp8_fp8((long)afr[KK], (long)b1v, a3, 0,0,0); \
                 } else { \
                     a0 = __builtin_amdgcn_mfma_f32_16x16x32_fp8_fp8((long)afr[KK], (long)b0, a0, 0,0,0); \
                     a2 = __builtin_amdgcn_mfma_f32_16x16x32_fp8_fp8((long)afr[KK], (long)b1v, a2, 0,0,0); \
                 } }
            REP32(MF, 0)
#undef MF
            accA = a0 + a1; accB = a2 + a3;
        } else {
            // layout-assumption-free VALU fallback (slow, correct)
            for (int bt = 0; bt < 2; ++bt) {
                float a16[16];
#pragma unroll
                for (int c = 0; c < 16; ++c) a16[c] = 0.f;
                for (int kk = 0; kk < 32; ++kk) {
                    const u64 av = afr[kk];
                    float ea0 = dec8((u32)av), ea1 = dec8((u32)(av>>8)), ea2 = dec8((u32)(av>>16)), ea3 = dec8((u32)(av>>24));
                    float ea4 = dec8((u32)(av>>32)), ea5 = dec8((u32)(av>>40)), ea6 = dec8((u32)(av>>48)), ea7 = dec8((u32)(av>>56));
#pragma unroll
                    for (int c = 0; c < 16; ++c) {
                        const uint2 bfr = wb[kk * KSTRIDE + bt * 64 + h * 16 + c];
                        const u64 bv = (u64)bfr.x | ((u64)bfr.y << 32);
                        float s = fmaf(ea0, dec8((u32)bv), 0.f);
                        s = fmaf(ea1, dec8((u32)(bv>>8)), s);  s = fmaf(ea2, dec8((u32)(bv>>16)), s);
                        s = fmaf(ea3, dec8((u32)(bv>>24)), s); s = fmaf(ea4, dec8((u32)(bv>>32)), s);
                        s = fmaf(ea5, dec8((u32)(bv>>40)), s); s = fmaf(ea6, dec8((u32)(bv>>48)), s);
                        s = fmaf(ea7, dec8((u32)(bv>>56)), s);
                        a16[c] += s;
                    }
                }
#pragma unroll
                for (int c = 0; c < 16; ++c) {
                    float v2 = a16[c];
                    v2 += __shfl_xor(v2, 16); v2 += __shfl_xor(v2, 32);
                    a16[c] = v2;
                }
                if (h == 0) {
#pragma unroll
                    for (int c = 0; c < 16; ++c) fbx[wv][myc][c] = a16[c];
                }
                __syncthreads();
                f32x4 r;
                r.x = fbx[wv][h*4+0][myc]; r.y = fbx[wv][h*4+1][myc];
                r.z = fbx[wv][h*4+2][myc]; r.w = fbx[wv][h*4+3][myc];
                if (bt == 0) accA = r; else accB = r;
                __syncthreads();
            }
        }

        // ---- 4. publish -> parity p^1; per-wave drain; barrier; block flag ----
        {
            u32* pb = wgrp + (p ^ 1) * PARW;
            const u32 pkA = pack4_fp8(accA.x * exp2f(fmaf(ffa.x, LOG2E_F, -Cme0)),
                                      accA.y * exp2f(fmaf(ffa.y, LOG2E_F, -Cme0)),
                                      accA.z * exp2f(fmaf(ffa.z, LOG2E_F, -Cme0)),
                                      accA.w * exp2f(fmaf(ffa.w, LOG2E_F, -Cme0)));
            const u32 pkB = pack4_fp8(accB.x * exp2f(fmaf(ffb.x, LOG2E_F, -Cme1)),
                                      accB.y * exp2f(fmaf(ffb.y, LOG2E_F, -Cme1)),
                                      accB.z * exp2f(fmaf(ffb.z, LOG2E_F, -Cme1)),
                                      accB.w * exp2f(fmaf(ffb.w, LOG2E_F, -Cme1)));
            __hip_atomic_store(&pb[myc * 256 + (growD >> 2)], pkA,
                               __ATOMIC_RELAXED, __HIP_MEMORY_SCOPE_AGENT);
            __hip_atomic_store(&pb[(16 + myc) * 256 + (growD >> 2)], pkB,
                               __ATOMIC_RELAXED, __HIP_MEMORY_SCOPE_AGENT);
        }
        asm volatile("s_waitcnt vmcnt(0)" ::: "memory");   // this wave's stores acked
        __syncthreads();                                    // all waves acked
        if (tid == 0)
            __hip_atomic_store(&fgrp[(p ^ 1) * 8 + rank], tag + 1u,
                               __ATOMIC_RELAXED, __HIP_MEMORY_SCOPE_AGENT);
    }

    if (rank == 0 && tid < CPG)
        Ssum[bwd * KCH + gl * CPG + tid] = Sacc;
}

// grid 545: c<512 dots | 512..543 emit partials | 544 trans-sum (R14/R15-proven placement)
__global__ void crf_dots_k(const u32* __restrict__ wbufs, const float* __restrict__ trans,
                           const float* __restrict__ feats, const int* __restrict__ tags,
                           const int* __restrict__ start_p, const int* __restrict__ stop_p,
                           double* __restrict__ dotv, double* __restrict__ sumyv,
                           double* __restrict__ finv, float* __restrict__ part,
                           float* __restrict__ tsum)
{
    __shared__ double red[256];
    __shared__ int tg[2048];
    __shared__ float redf[256];
    const int c = blockIdx.x;
    const int tid = threadIdx.x;     // 256

    if (c < KCH) {
        const int GRPW = 2 * PARW;
        const u32* y = wbufs + (size_t)(c >> 5) * GRPW + (c & 31) * 256;
        const u32* z = wbufs + (size_t)(16 + (c >> 5)) * GRPW + (c & 31) * 256;
        const u32* ym1 = (c > 0)
            ? (wbufs + (size_t)((c - 1) >> 5) * GRPW + ((c - 1) & 31) * 256) : nullptr;
        const int stop = *stop_p;

        const u32 wy = y[tid];
        double sy = 0, dt = 0, fn = 0;
#pragma unroll
        for (int b = 0; b < 4; ++b) {
            const double yv = (double)dec8(wy >> (8 * b));
            sy += yv;
            if (c == KCH - 1)
                fn += yv * (double)__expf(trans[(size_t)stop * NTAGS + 4 * tid + b]);
        }
        if (c > 0) {
            const u32 wz = z[tid], wm = ym1[tid];
#pragma unroll
            for (int b = 0; b < 4; ++b)
                dt += (double)dec8(wz >> (8 * b)) * (double)dec8(wm >> (8 * b));
        }
        red[tid] = sy; __syncthreads();
        for (int s = 128; s > 0; s >>= 1) { if (tid < s) red[tid] += red[tid + s]; __syncthreads(); }
        if (tid == 0) sumyv[c] = red[0];
        __syncthreads();
        red[tid] = dt; __syncthreads();
        for (int s = 128; s > 0; s >>= 1) { if (tid < s) red[tid] += red[tid + s]; __syncthreads(); }
        if (tid == 0 && c > 0) dotv[c] = red[0];
        __syncthreads();
        red[tid] = fn; __syncthreads();
        for (int s = 128; s > 0; s >>= 1) { if (tid < s) red[tid] += red[tid + s]; __syncthreads(); }
        if (tid == 0 && c == KCH - 1) finv[0] = red[0];
        if (tid == 0 && c == 0) {
            const int st = *start_p;
            dotv[0] = (double)dec8(z[st >> 2] >> (8 * (st & 3)));
        }
    } else if (c < KCH + 32) {
        const int bb = c - KCH, cch = bb >> 2, jb = bb & 3;
        for (int q = tid; q < 2048; q += 256) tg[q] = tags[cch * 2048 + q];
        __syncthreads();
        const int j = jb * 256 + tid;
        float acc = 0.f;
#pragma unroll 8
        for (int k = 0; k < 2048; ++k) acc += feats[(size_t)tg[k] * NTAGS + j];
        part[cch * NTAGS + j] = acc;
    } else {
        const int start = *start_p;
        float acc = 0.f;
        for (int k = 0; k < 64; ++k) {
            const int t = tid * 64 + k;
            const int prev = (t == 0) ? start : tags[t - 1];
            acc += trans[(size_t)tags[t] * NTAGS + prev];
        }
        redf[tid] = acc;
        __syncthreads();
        for (int s = 128; s > 0; s >>= 1) { if (tid < s) redf[tid] += redf[tid + s]; __syncthreads(); }
        if (tid == 0) *tsum = redf[0];
    }
}

// finish: parallel chunk-composition (fs) + output vector
__global__ void crf_finish_k(const double* __restrict__ Ssum, const double* __restrict__ dotv,
                             const double* __restrict__ sumyv, const double* __restrict__ finv,
                             const float* __restrict__ tsum, const float* __restrict__ part,
                             const float* __restrict__ trans, const int* __restrict__ tags,
                             const int* __restrict__ stop_p, float* __restrict__ out)
{
    __shared__ double red[1024];
    __shared__ float fsv;
    const int tid = threadIdx.x;   // 1024
    const double* Ssf = Ssum;
    const double* Ssb = Ssum + KCH;
    double t = 0.0;
    if (tid == 0)
        t = log2(dotv[0]) + Ssb[0] - log2(sumyv[0]) - Ssf[0]
          + log2(finv[0]) + Ssf[KCH - 1];
    else if (tid < KCH)
        t = log2(dotv[tid]) + Ssb[tid] + Ssf[tid - 1] - log2(sumyv[tid]) - Ssf[tid];
    red[tid] = t; __syncthreads();
    for (int s = 512; s > 0; s >>= 1) { if (tid < s) red[tid] += red[tid + s]; __syncthreads(); }
    if (tid == 0) fsv = (float)(LN2_D * red[0]);
    __syncthreads();
    float e = 0.f;
    for (int cc = 0; cc < 8; ++cc) e += part[cc * NTAGS + tid];
    const int stop = *stop_p;
    const int last = tags[SEQLEN - 1];
    out[tid] = fsv - (tsum[0] + e + trans[(size_t)stop * NTAGS + last]);
}

extern "C" void kernel_launch(void* const* d_in, const int* in_sizes, int n_in,
                              void* d_out, int out_size, void* d_ws, size_t ws_size,
                              hipStream_t stream) {
    const float* feats = (const float*)d_in[0];
    const float* trans = (const float*)d_in[1];
    const int* tags    = (const int*)d_in[2];
    const int* start_p = (const int*)d_in[3];
    const int* stop_p  = (const int*)d_in[4];
    float* out = (float*)d_out;

    // ws: wire 2MB | part 32KB | Ssum 8KB | dotv 4KB | sumyv 4KB | finv/tsum | flags
    char* ws = (char*)d_ws;
    u32* wbufs    = (u32*)(ws + 0);
    float* part   = (float*)(ws + 2097152);
    double* Ssum  = (double*)(ws + 2129920);
    double* dotv  = (double*)(ws + 2138112);
    double* sumyv = (double*)(ws + 2142208);
    double* finv  = (double*)(ws + 2146304);
    float* tsum   = (float*)(ws + 2146312);
    u32* flags    = (u32*)(ws + 2146816);

    (void)hipFuncSetAttribute((const void*)crf_scan_k,
                              hipFuncAttributeMaxDynamicSharedMemorySize,
                              2 * 32 * KSTRIDE * 8);

    crf_prep_k<<<1, 256, 0, stream>>>(flags);
    crf_scan_k<<<NGROUP * GPB, TPB, 2 * 32 * KSTRIDE * 8, stream>>>(feats, trans, wbufs,
                                                                    flags, Ssum);
    crf_dots_k<<<KCH + 33, 256, 0, stream>>>(wbufs, trans, feats, tags, start_p, stop_p,
                                             dotv, sumyv, finv, part, tsum);
    crf_finish_k<<<1, 1024, 0, stream>>>(Ssum, dotv, sumyv, finv, tsum, part, trans, tags,
                                         stop_p, out);
}

// Round 19
// 262.333 us; speedup vs baseline: 2.9594x; 1.2407x over previous
//
#include <hip/hip_runtime.h>
#include <stdint.h>

#define LOG2E_F 1.4426950408889634f
#define LN2_D   0.6931471805599453
#define SEQLEN  16384
#define NTAGS   1024
#define TPB     512
#define NGROUP  32        // 16 fwd + 16 bwd groups
#define GPB     8
#define ROWS    128
#define CPG     32        // chunk-columns per group (2 MFMA B-tiles)
#define LSEG    32        // steps per chunk
#define KCH     512       // chunks per direction
#define COFF    13.0f
#define GUARD_MAX 100000
#define PARW    (CPG * 256)   // tagless wire: 256 u32 (1024 fp8 rows) per col
#define KSTRIDE 129           // uint2 stride per kk: 516 dwords = 4 mod 32 -> 2-way free

typedef float f32x2 __attribute__((ext_vector_type(2)));
typedef float f32x4 __attribute__((ext_vector_type(4)));
typedef uint32_t u32;
typedef uint64_t u64;

#define REP4(M, B)   M(B) M((B)+1) M((B)+2) M((B)+3)
#define REP16(M, B)  REP4(M, B) REP4(M, (B)+4) REP4(M, (B)+8) REP4(M, (B)+12)
#define REP32(M, B)  REP16(M, B) REP16(M, (B)+16)

#if __has_builtin(__builtin_amdgcn_cvt_pk_fp8_f32) && __has_builtin(__builtin_amdgcn_cvt_pk_f32_fp8)
__device__ __forceinline__ u32 pack4_fp8(float x0, float x1, float x2, float x3) {
    int v = __builtin_amdgcn_cvt_pk_fp8_f32(x0, x1, 0, false);
    v = __builtin_amdgcn_cvt_pk_fp8_f32(x2, x3, v, true);
    return (u32)v;
}
__device__ __forceinline__ float dec8(u32 b) {
    f32x2 r = (f32x2)__builtin_amdgcn_cvt_pk_f32_fp8((int)(b & 0xFFu), false);
    return r.x;
}
#else
__device__ __forceinline__ u32 enc1_fp8(float x) {
    if (x >= 448.f) return 0x7Eu;
    if (x < 0.015625f) { int m = (int)(x * 512.f + 0.5f); return (u32)m; }
    u32 u = __float_as_uint(x);
    u += 0x7FFFFu + ((u >> 20) & 1u);
    int e32 = (int)(u >> 23) - 127;
    if (e32 > 8) return 0x7Eu;
    return (u32)(((e32 + 7) << 3) | ((u >> 20) & 7u));
}
__device__ __forceinline__ u32 pack4_fp8(float x0, float x1, float x2, float x3) {
    return enc1_fp8(x0) | (enc1_fp8(x1) << 8) | (enc1_fp8(x2) << 16) | (enc1_fp8(x3) << 24);
}
__device__ __forceinline__ float dec8(u32 b) {
    b &= 0xFFu;
    u32 e = (b >> 3) & 0xFu, m = b & 7u;
    if (e == 0) return (float)m * 0.001953125f;
    return __uint_as_float(((e + 120u) << 23) | (m << 20));
}
#endif

// prep: clear block-level flags only (1 block, ~3 us)
__global__ void crf_prep_k(u32* __restrict__ flags) {
    const int tid = threadIdx.x;   // 256
    for (int i = tid; i < NGROUP * 16; i += 256)
        __hip_atomic_store(&flags[i], 0xFFFFu, __ATOMIC_RELAXED, __HIP_MEMORY_SCOPE_AGENT);
}

__global__ __launch_bounds__(TPB, 1) void crf_scan_k(
    const float* __restrict__ feats, const float* __restrict__ trans,
    const int* __restrict__ tags, const int* __restrict__ start_p,
    u32* __restrict__ wbufs, u32* __restrict__ flags, double* __restrict__ Ssum,
    float* __restrict__ part, float* __restrict__ tpart)
{
    extern __shared__ uint2 wBf[];       // [2][32][KSTRIDE] MFMA B slots
    __shared__ u32 cmaxb[2][CPG];
    __shared__ float fbx[8][16][17];     // fallback transpose buffer
    __shared__ int okf, deadf;

    const int tid = threadIdx.x;
    const int l = tid & 63, wv = tid >> 6;
    const int g = blockIdx.x & 31, rank = blockIdx.x >> 5;   // ranks 32 apart
    const int bwd = g >> 4, gl = g & 15;
    const int row0 = rank * ROWS;
    const int pc = tid >> 4, pq = tid & 15;    // reader: col 0..31, word-slice 0..15
    const int myc = l & 15, h = l >> 4;
    const int growA = row0 + wv * 16 + myc;
    const int growD = row0 + wv * 16 + h * 4;
    const int sb = (pc >> 4) * 64 + (pc & 15);
    u32* wgrp = wbufs + (size_t)g * (2 * PARW);
    u32* fgrp = flags + g * 16;                // [parity][rank]

    if (tid == 0) { okf = 1; deadf = 0; }
    double Sacc = bwd ? 3.0 : 0.0;             // meaningful for tid < CPG

    // ---- init publish (parity 0), tagless — R13-proven ----
    for (int f = tid; f < CPG * 32; f += TPB) {
        const int c = f >> 5, q = f & 31;      // col, word-in-block (4 rows/word)
        u32 pk;
        if (!bwd) pk = 0x38383838u;            // fp8(1.0) x4
        else {
            const int t = (gl * CPG + c) * LSEG + LSEG - 1;
            const int j0 = row0 + 4 * q;
            const float4 fv = *(const float4*)&feats[(size_t)t * NTAGS + j0];
            pk = pack4_fp8(exp2f(fv.x * LOG2E_F - 3.0f), exp2f(fv.y * LOG2E_F - 3.0f),
                           exp2f(fv.z * LOG2E_F - 3.0f), exp2f(fv.w * LOG2E_F - 3.0f));
        }
        __hip_atomic_store(&wgrp[c * 256 + (row0 >> 2) + q], pk,
                           __ATOMIC_RELAXED, __HIP_MEMORY_SCOPE_AGENT);
    }
    asm volatile("s_waitcnt vmcnt(0)" ::: "memory");   // init data acked (per wave)
    __syncthreads();                                    // all waves acked
    if (tid == 0)
        __hip_atomic_store(&fgrp[0 * 8 + rank], 0u, __ATOMIC_RELAXED, __HIP_MEMORY_SCOPE_AGENT);

    // ---- stage E as persistent A-fragments (fp8, 64 VGPR) — R10-proven ----
    u64 afr[32];
#define STG(KK) { \
        const int kb = (KK) * 32 + h * 8; \
        float x0,x1,x2,x3,x4,x5,x6,x7; \
        if (!bwd) { \
            const float4 t0 = *(const float4*)&trans[(size_t)growA * NTAGS + kb]; \
            const float4 t1 = *(const float4*)&trans[(size_t)growA * NTAGS + kb + 4]; \
            x0=t0.x; x1=t0.y; x2=t0.z; x3=t0.w; x4=t1.x; x5=t1.y; x6=t1.z; x7=t1.w; \
        } else { \
            x0 = trans[(size_t)(kb+0)*NTAGS + growA]; x1 = trans[(size_t)(kb+1)*NTAGS + growA]; \
            x2 = trans[(size_t)(kb+2)*NTAGS + growA]; x3 = trans[(size_t)(kb+3)*NTAGS + growA]; \
            x4 = trans[(size_t)(kb+4)*NTAGS + growA]; x5 = trans[(size_t)(kb+5)*NTAGS + growA]; \
            x6 = trans[(size_t)(kb+6)*NTAGS + growA]; x7 = trans[(size_t)(kb+7)*NTAGS + growA]; \
        } \
        const u32 lo = pack4_fp8(exp2f(x0*LOG2E_F), exp2f(x1*LOG2E_F), exp2f(x2*LOG2E_F), exp2f(x3*LOG2E_F)); \
        const u32 hi = pack4_fp8(exp2f(x4*LOG2E_F), exp2f(x5*LOG2E_F), exp2f(x6*LOG2E_F), exp2f(x7*LOG2E_F)); \
        afr[KK] = (u64)lo | ((u64)hi << 32); }
    REP32(STG, 0)
#undef STG

    // ---- MFMA layout self-check (exact small-int, asymmetric) — R10-proven ----
    {
        float av0,av1,av2,av3,av4,av5,av6,av7, bv0,bv1,bv2,bv3,bv4,bv5,bv6,bv7;
#define TV(I) { const int k = h*8 + (I); \
        const float a_ = (float)((myc + k) & 3); \
        const float b_ = (float)(((k ^ myc) & 3) + 1); \
        if ((I)==0){av0=a_;bv0=b_;} if ((I)==1){av1=a_;bv1=b_;} \
        if ((I)==2){av2=a_;bv2=b_;} if ((I)==3){av3=a_;bv3=b_;} \
        if ((I)==4){av4=a_;bv4=b_;} if ((I)==5){av5=a_;bv5=b_;} \
        if ((I)==6){av6=a_;bv6=b_;} if ((I)==7){av7=a_;bv7=b_;} }
        TV(0) TV(1) TV(2) TV(3) TV(4) TV(5) TV(6) TV(7)
#undef TV
        const u64 at = (u64)pack4_fp8(av0,av1,av2,av3) | ((u64)pack4_fp8(av4,av5,av6,av7) << 32);
        const u64 bt = (u64)pack4_fp8(bv0,bv1,bv2,bv3) | ((u64)pack4_fp8(bv4,bv5,bv6,bv7) << 32);
        f32x4 dz = {0.f, 0.f, 0.f, 0.f};
        dz = __builtin_amdgcn_mfma_f32_16x16x32_fp8_fp8((long)at, (long)bt, dz, 0, 0, 0);
        bool good = true;
#pragma unroll
        for (int v = 0; v < 4; ++v) {
            const int row = h * 4 + v;
            float e = 0.f;
            for (int k = 0; k < 32; ++k)
                e += (float)(((row + k) & 3) * (((k ^ myc) & 3) + 1));
            good = good && (dz[v] == e);
        }
        if (!good) okf = 0;
    }
    __syncthreads();
    const bool fb = (okf == 0);

    for (int tau = 0; tau < LSEG; ++tau) {
        const int p = tau & 1;
        const u32 tag = (u32)tau;

        // feat prefetch (both col-tiles), issued before discovery
        float4 ffa = make_float4(0.f,0.f,0.f,0.f), ffb = make_float4(0.f,0.f,0.f,0.f);
        {
            int t = -1;
            if (!bwd) t = tau; else if (tau <= LSEG - 2) t = LSEG - 2 - tau;
            if (t >= 0) {
                const int ca = gl * CPG + myc;
                ffa = *(const float4*)&feats[(size_t)(ca * LSEG + t) * NTAGS + growD];
                ffb = *(const float4*)&feats[(size_t)((ca + 16) * LSEG + t) * NTAGS + growD];
            }
        }

        // ---- 1. flag discovery: wave 0 only ----
        if (wv == 0) {
            int guard = 0;
            u32 fv = tag;
            for (;;) {
                if (l < GPB)
                    fv = __hip_atomic_load(&fgrp[p * 8 + l],
                                           __ATOMIC_RELAXED, __HIP_MEMORY_SCOPE_AGENT);
                if (__all(fv == tag)) break;
                if (++guard > GUARD_MAX) { deadf = 1; break; }
            }
        }
        __syncthreads();               // flags seen; deadf visible
        if (deadf) break;

        // ---- 2. tagless bulk read: 16 words = 64 rows of col pc ----
        u32 w[16];
        {
            const u32* pp = wgrp + p * PARW + pc * 256 + pq * 16;
#pragma unroll
            for (int q = 0; q < 8; ++q) {
                const u64 v = __hip_atomic_load((const u64*)(pp + 2 * q),
                                                __ATOMIC_RELAXED, __HIP_MEMORY_SCOPE_AGENT);
                w[2 * q] = (u32)v; w[2 * q + 1] = (u32)(v >> 32);
            }
        }
        // B-slot writes (stride KSTRIDE: 2-way bank aliasing only)
        {
#pragma unroll
            for (int h2 = 0; h2 < 4; ++h2) {
                wBf[((size_t)p * 32 + 2 * pq)     * KSTRIDE + sb + h2 * 16] = make_uint2(w[2*h2],   w[2*h2+1]);
                wBf[((size_t)p * 32 + 2 * pq + 1) * KSTRIDE + sb + h2 * 16] = make_uint2(w[8+2*h2], w[9+2*h2]);
            }
        }
        // col byte-max (fp8 e4m3 positive: integer order = value order)
        {
            u32 bm = 0;
#pragma unroll
            for (int q = 0; q < 16; ++q) {
                bm = max(bm, w[q] & 0xFFu); bm = max(bm, (w[q] >> 8) & 0xFFu);
                bm = max(bm, (w[q] >> 16) & 0xFFu); bm = max(bm, w[q] >> 24);
            }
#pragma unroll
            for (int o = 8; o > 0; o >>= 1) bm = max(bm, (u32)__shfl_xor((int)bm, o));
            if (pq == 0) cmaxb[p][pc] = bm;
        }
        __syncthreads();                 // B1: slots + cmax ready

        const float Cme0 = __log2f(dec8(cmaxb[p][myc])) + COFF;
        const float Cme1 = __log2f(dec8(cmaxb[p][16 + myc])) + COFF;
        if (tid < CPG) Sacc += (double)(__log2f(dec8(cmaxb[p][tid])) + COFF);

        // ---- 3. D = E(128x1024) x w(1024x32): 2 B-tiles, 64 MFMA ----
        f32x4 accA, accB;
        const uint2* wb = &wBf[(size_t)p * 32 * KSTRIDE];
        if (!fb) {
            f32x4 a0 = {0.f,0.f,0.f,0.f}, a1 = {0.f,0.f,0.f,0.f};
            f32x4 a2 = {0.f,0.f,0.f,0.f}, a3 = {0.f,0.f,0.f,0.f};
#define MF(KK) { const uint2 f0 = wb[(KK)*KSTRIDE + l]; \
                 const u64 b0 = (u64)f0.x | ((u64)f0.y << 32); \
                 const uint2 f1 = wb[(KK)*KSTRIDE + 64 + l]; \
                 const u64 b1v = (u64)f1.x | ((u64)f1.y << 32); \
                 if ((KK) & 1) { \
                     a1 = __builtin_amdgcn_mfma_f32_16x16x32_fp8_fp8((long)afr[KK], (long)b0, a1, 0,0,0); \
                     a3 = __builtin_amdgcn_mfma_f32_16x16x32_fp8_fp8((long)afr[KK], (long)b1v, a3, 0,0,0); \
                 } else { \
                     a0 = __builtin_amdgcn_mfma_f32_16x16x32_fp8_fp8((long)afr[KK], (long)b0, a0, 0,0,0); \
                     a2 = __builtin_amdgcn_mfma_f32_16x16x32_fp8_fp8((long)afr[KK], (long)b1v, a2, 0,0,0); \
                 } }
            REP32(MF, 0)
#undef MF
            accA = a0 + a1; accB = a2 + a3;
        } else {
            // layout-assumption-free VALU fallback (slow, correct)
            for (int bt = 0; bt < 2; ++bt) {
                float a16[16];
#pragma unroll
                for (int c = 0; c < 16; ++c) a16[c] = 0.f;
                for (int kk = 0; kk < 32; ++kk) {
                    const u64 av = afr[kk];
                    float ea0 = dec8((u32)av), ea1 = dec8((u32)(av>>8)), ea2 = dec8((u32)(av>>16)), ea3 = dec8((u32)(av>>24));
                    float ea4 = dec8((u32)(av>>32)), ea5 = dec8((u32)(av>>40)), ea6 = dec8((u32)(av>>48)), ea7 = dec8((u32)(av>>56));
#pragma unroll
                    for (int c = 0; c < 16; ++c) {
                        const uint2 bfr = wb[kk * KSTRIDE + bt * 64 + h * 16 + c];
                        const u64 bv = (u64)bfr.x | ((u64)bfr.y << 32);
                        float s = fmaf(ea0, dec8((u32)bv), 0.f);
                        s = fmaf(ea1, dec8((u32)(bv>>8)), s);  s = fmaf(ea2, dec8((u32)(bv>>16)), s);
                        s = fmaf(ea3, dec8((u32)(bv>>24)), s); s = fmaf(ea4, dec8((u32)(bv>>32)), s);
                        s = fmaf(ea5, dec8((u32)(bv>>40)), s); s = fmaf(ea6, dec8((u32)(bv>>48)), s);
                        s = fmaf(ea7, dec8((u32)(bv>>56)), s);
                        a16[c] += s;
                    }
                }
#pragma unroll
                for (int c = 0; c < 16; ++c) {
                    float v2 = a16[c];
                    v2 += __shfl_xor(v2, 16); v2 += __shfl_xor(v2, 32);
                    a16[c] = v2;
                }
                if (h == 0) {
#pragma unroll
                    for (int c = 0; c < 16; ++c) fbx[wv][myc][c] = a16[c];
                }
                __syncthreads();
                f32x4 r;
                r.x = fbx[wv][h*4+0][myc]; r.y = fbx[wv][h*4+1][myc];
                r.z = fbx[wv][h*4+2][myc]; r.w = fbx[wv][h*4+3][myc];
                if (bt == 0) accA = r; else accB = r;
                __syncthreads();
            }
        }

        // ---- 4. publish -> parity p^1; per-wave drain; barrier; block flag ----
        {
            u32* pb = wgrp + (p ^ 1) * PARW;
            const u32 pkA = pack4_fp8(accA.x * exp2f(fmaf(ffa.x, LOG2E_F, -Cme0)),
                                      accA.y * exp2f(fmaf(ffa.y, LOG2E_F, -Cme0)),
                                      accA.z * exp2f(fmaf(ffa.z, LOG2E_F, -Cme0)),
                                      accA.w * exp2f(fmaf(ffa.w, LOG2E_F, -Cme0)));
            const u32 pkB = pack4_fp8(accB.x * exp2f(fmaf(ffb.x, LOG2E_F, -Cme1)),
                                      accB.y * exp2f(fmaf(ffb.y, LOG2E_F, -Cme1)),
                                      accB.z * exp2f(fmaf(ffb.z, LOG2E_F, -Cme1)),
                                      accB.w * exp2f(fmaf(ffb.w, LOG2E_F, -Cme1)));
            __hip_atomic_store(&pb[myc * 256 + (growD >> 2)], pkA,
                               __ATOMIC_RELAXED, __HIP_MEMORY_SCOPE_AGENT);
            __hip_atomic_store(&pb[(16 + myc) * 256 + (growD >> 2)], pkB,
                               __ATOMIC_RELAXED, __HIP_MEMORY_SCOPE_AGENT);
        }
        asm volatile("s_waitcnt vmcnt(0)" ::: "memory");   // this wave's stores acked
        __syncthreads();                                    // all waves acked
        if (tid == 0)
            __hip_atomic_store(&fgrp[(p ^ 1) * 8 + rank], tag + 1u,
                               __ATOMIC_RELAXED, __HIP_MEMORY_SCOPE_AGENT);
    }

    if (rank == 0 && tid < CPG)
        Ssum[bwd * KCH + gl * CPG + tid] = Sacc;

    // ---- tail: emit + trans partials (off critical path, all 256 blocks) ----
    __syncthreads();
    {
        int* tg = (int*)wBf;                  // 2048 ints (reuse dynamic LDS)
        float* psum = (float*)(tg + 2048);    // [16][33] padded
        const int cch = blockIdx.x >> 5;      // 0..7
        const int jsl = (blockIdx.x & 31) * 32;
        for (int q2 = tid; q2 < 2048; q2 += TPB) tg[q2] = tags[cch * 2048 + q2];
        __syncthreads();
        const int jj = jsl + (tid & 31);
        const int ks = tid >> 5;              // 0..15, 128 k each
        const int kbase = ks * 128;
        float acc2 = 0.f;
#pragma unroll 8
        for (int k = 0; k < 128; ++k)
            acc2 += feats[(size_t)tg[kbase + k] * NTAGS + jj];
        psum[ks * 33 + (tid & 31)] = acc2;
        __syncthreads();
        if (tid < 32) {
            float s2 = 0.f;
#pragma unroll
            for (int q2 = 0; q2 < 16; ++q2) s2 += psum[q2 * 33 + tid];
            part[cch * NTAGS + jsl + tid] = s2;
        }
        // trans partial over t in [bid*64, bid*64+64)
        if (tid < 64) {
            const int t = blockIdx.x * 64 + tid;
            const int prev = (t == 0) ? (*start_p) : tags[t - 1];
            float ta = trans[(size_t)tags[t] * NTAGS + prev];
#pragma unroll
            for (int o = 32; o > 0; o >>= 1) ta += __shfl_xor(ta, o);
            if (tid == 0) tpart[blockIdx.x] = ta;
        }
    }
}

// dots: sumy[c]=1'y_c ; dot[c]=z_c.y_{c-1} (c>0), dot[0]=z_0[start]; fin=y_{K-1}.exp(T[stop,:])
__global__ void crf_dots_k(const u32* __restrict__ wbufs, const float* __restrict__ trans,
                           const int* __restrict__ start_p, const int* __restrict__ stop_p,
                           double* __restrict__ dotv, double* __restrict__ sumyv,
                           double* __restrict__ finv)
{
    const int c = blockIdx.x;        // 0..511
    const int tid = threadIdx.x;     // 256 (one word each; 4 rows/word)
    __shared__ double red[256];
    const int GRPW = 2 * PARW;
    const u32* y = wbufs + (size_t)(c >> 5) * GRPW + (c & 31) * 256;
    const u32* z = wbufs + (size_t)(16 + (c >> 5)) * GRPW + (c & 31) * 256;
    const u32* ym1 = (c > 0)
        ? (wbufs + (size_t)((c - 1) >> 5) * GRPW + ((c - 1) & 31) * 256) : nullptr;
    const int stop = *stop_p;

    const u32 wy = y[tid];
    double sy = 0, dt = 0, fn = 0;
#pragma unroll
    for (int b = 0; b < 4; ++b) {
        const double yv = (double)dec8(wy >> (8 * b));
        sy += yv;
        if (c == KCH - 1)
            fn += yv * (double)__expf(trans[(size_t)stop * NTAGS + 4 * tid + b]);
    }
    if (c > 0) {
        const u32 wz = z[tid], wm = ym1[tid];
#pragma unroll
        for (int b = 0; b < 4; ++b)
            dt += (double)dec8(wz >> (8 * b)) * (double)dec8(wm >> (8 * b));
    }
    red[tid] = sy; __syncthreads();
    for (int s = 128; s > 0; s >>= 1) { if (tid < s) red[tid] += red[tid + s]; __syncthreads(); }
    if (tid == 0) sumyv[c] = red[0];
    __syncthreads();
    red[tid] = dt; __syncthreads();
    for (int s = 128; s > 0; s >>= 1) { if (tid < s) red[tid] += red[tid + s]; __syncthreads(); }
    if (tid == 0 && c > 0) dotv[c] = red[0];
    __syncthreads();
    red[tid] = fn; __syncthreads();
    for (int s = 128; s > 0; s >>= 1) { if (tid < s) red[tid] += red[tid + s]; __syncthreads(); }
    if (tid == 0 && c == KCH - 1) finv[0] = red[0];
    if (tid == 0 && c == 0) {
        const int st = *start_p;
        dotv[0] = (double)dec8(z[st >> 2] >> (8 * (st & 3)));
    }
}

// finish: parallel chunk-composition (fs) + tsum from partials + output vector
__global__ void crf_finish_k(const double* __restrict__ Ssum, const double* __restrict__ dotv,
                             const double* __restrict__ sumyv, const double* __restrict__ finv,
                             const float* __restrict__ tpart, const float* __restrict__ part,
                             const float* __restrict__ trans, const int* __restrict__ tags,
                             const int* __restrict__ stop_p, float* __restrict__ out)
{
    __shared__ double red[1024];
    __shared__ float fsv, tsumv;
    const int tid = threadIdx.x;   // 1024
    const double* Ssf = Ssum;
    const double* Ssb = Ssum + KCH;
    double t = 0.0;
    if (tid == 0)
        t = log2(dotv[0]) + Ssb[0] - log2(sumyv[0]) - Ssf[0]
          + log2(finv[0]) + Ssf[KCH - 1];
    else if (tid < KCH)
        t = log2(dotv[tid]) + Ssb[tid] + Ssf[tid - 1] - log2(sumyv[tid]) - Ssf[tid];
    red[tid] = t; __syncthreads();
    for (int s = 512; s > 0; s >>= 1) { if (tid < s) red[tid] += red[tid + s]; __syncthreads(); }
    if (tid == 0) fsv = (float)(LN2_D * red[0]);
    __syncthreads();
    // tsum = sum of 256 trans partials
    red[tid] = (tid < 256) ? (double)tpart[tid] : 0.0;
    __syncthreads();
    for (int s = 512; s > 0; s >>= 1) { if (tid < s) red[tid] += red[tid + s]; __syncthreads(); }
    if (tid == 0) tsumv = (float)red[0];
    __syncthreads();
    float e = 0.f;
    for (int cc = 0; cc < 8; ++cc) e += part[cc * NTAGS + tid];
    const int stop = *stop_p;
    const int last = tags[SEQLEN - 1];
    out[tid] = fsv - (tsumv + e + trans[(size_t)stop * NTAGS + last]);
}

extern "C" void kernel_launch(void* const* d_in, const int* in_sizes, int n_in,
                              void* d_out, int out_size, void* d_ws, size_t ws_size,
                              hipStream_t stream) {
    const float* feats = (const float*)d_in[0];
    const float* trans = (const float*)d_in[1];
    const int* tags    = (const int*)d_in[2];
    const int* start_p = (const int*)d_in[3];
    const int* stop_p  = (const int*)d_in[4];
    float* out = (float*)d_out;

    // ws: wire 2MB | part 32KB | Ssum 8KB | dotv 4KB | sumyv 4KB | finv | flags 2KB | tpart 1KB
    char* ws = (char*)d_ws;
    u32* wbufs    = (u32*)(ws + 0);
    float* part   = (float*)(ws + 2097152);
    double* Ssum  = (double*)(ws + 2129920);
    double* dotv  = (double*)(ws + 2138112);
    double* sumyv = (double*)(ws + 2142208);
    double* finv  = (double*)(ws + 2146304);
    u32* flags    = (u32*)(ws + 2146816);
    float* tpart  = (float*)(ws + 2148864);

    (void)hipFuncSetAttribute((const void*)crf_scan_k,
                              hipFuncAttributeMaxDynamicSharedMemorySize,
                              2 * 32 * KSTRIDE * 8);

    crf_prep_k<<<1, 256, 0, stream>>>(flags);
    crf_scan_k<<<NGROUP * GPB, TPB, 2 * 32 * KSTRIDE * 8, stream>>>(
        feats, trans, tags, start_p, wbufs, flags, Ssum, part, tpart);
    crf_dots_k<<<KCH, 256, 0, stream>>>(wbufs, trans, start_p, stop_p, dotv, sumyv, finv);
    crf_finish_k<<<1, 1024, 0, stream>>>(Ssum, dotv, sumyv, finv, tpart, part, trans, tags,
                                         stop_p, out);
}